// Round 26
// baseline (555.699 us; speedup 1.0000x reference)
//
#include <hip/hip_runtime.h>
#include <hip/hip_bf16.h>

typedef __hip_bfloat16 bf16;
typedef __attribute__((ext_vector_type(8))) short short8;
typedef __attribute__((ext_vector_type(4))) float f32x4;

static __device__ __forceinline__ float b2f(bf16 v){ return __bfloat162float(v); }
static __device__ __forceinline__ int clampi(int v, int lo, int hi){
  return v < lo ? lo : (v > hi ? hi : v);
}
static __device__ __forceinline__ float rw32(float v){
  #pragma unroll
  for (int m=16;m>=1;m>>=1) v += __shfl_xor(v,m,64);
  return v;
}
static __device__ __forceinline__ float rw64(float v){
  #pragma unroll
  for (int m=32;m>=1;m>>=1) v += __shfl_xor(v,m,64);
  return v;
}

constexpr int Nn = 30000;   // nodes
constexpr int E0 = 480000;  // edges (no self loops)
constexpr int EP = E0 + Nn; // edges incl self loops = 510000
constexpr int Gg = 128;     // graphs
constexpr int Vv = 10000;   // vocab size of emb

// ---------------- diagnostic flag (fp32 out) ----------------
__global__ void k_flag(float* __restrict__ out, float v){
  int t = blockIdx.x*blockDim.x + threadIdx.x;
  if (t < Gg*2) out[t] = v;
}

// ---------------- zero both CSR scratch arrays in one launch ----------------
__global__ void k_zero2(int* __restrict__ counts, int* __restrict__ cursor){
  int t = blockIdx.x*blockDim.x + threadIdx.x;
  if (t < Nn){ counts[t] = 0; cursor[t] = 0; }
}

// ---------------- CSR build (by dst) ----------------
__global__ void k_count(const int* __restrict__ ei, int* __restrict__ counts){
  int e = blockIdx.x*blockDim.x + threadIdx.x;
  if (e >= EP) return;
  int dst = (e < E0) ? clampi(ei[E0 + e], 0, Nn-1) : (e - E0);
  atomicAdd(&counts[dst], 1);
}

__global__ void k_scan(const int* __restrict__ counts, int* __restrict__ row_start){
  __shared__ int s[256];
  constexpr int CH = (Nn + 255) / 256;  // 118
  int tid = threadIdx.x;
  int base = tid*CH;
  int t_sum = 0;
  for (int j=0;j<CH;j++){ int i = base+j; if (i<Nn) t_sum += counts[i]; }
  s[tid] = t_sum; __syncthreads();
  for (int off=1; off<256; off<<=1){
    int v = (tid>=off) ? s[tid-off] : 0;
    __syncthreads();
    s[tid] += v; __syncthreads();
  }
  int run = s[tid] - t_sum; // exclusive prefix
  for (int j=0;j<CH;j++){ int i = base+j; if (i<Nn){ row_start[i] = run; run += counts[i]; } }
  if (tid == 255) row_start[Nn] = s[255];
}

__global__ void k_fill(const int* __restrict__ ei, const int* __restrict__ row_start,
                       int* __restrict__ cursor, int* __restrict__ csr_src){
  int e = blockIdx.x*blockDim.x + threadIdx.x;
  if (e >= EP) return;
  int src = (e < E0) ? clampi(ei[e],      0, Nn-1) : (e - E0);
  int dst = (e < E0) ? clampi(ei[E0 + e], 0, Nn-1) : (e - E0);
  int pos = atomicAdd(&cursor[dst], 1);
  int i = row_start[dst] + pos;
  if (i < 0 || i >= EP) return;
  csr_src[i] = src;
}

// ---------------- embedding gather (emb fp32 -> x bf16) ----------------
__global__ void k_gather(const float* __restrict__ emb, const int* __restrict__ ids,
                         bf16* __restrict__ x){
  int t = blockIdx.x*blockDim.x + threadIdx.x;
  if (t >= Nn*16) return;
  int n = t >> 4, c = t & 15;
  int id = clampi(ids[n], 0, Vv-1);
  x[t] = __float2bfloat16(emb[id*16 + c]);
}

// ---------------- pack ALL six W [K][F] fp32 -> Wb [F][Kp] bf16 in one launch ----------------
// segments: 0,1: K=16,F=96,Kp=32 (3072) | 2,3: K=96,F=192,Kp=96 (18432) | 4,5: K=192,F=64,Kp=192 (12288)
__global__ void k_packAll(const float* __restrict__ W0l, const float* __restrict__ W0r,
                          const float* __restrict__ W1l, const float* __restrict__ W1r,
                          const float* __restrict__ W2l, const float* __restrict__ W2r,
                          bf16* __restrict__ B0l, bf16* __restrict__ B0r,
                          bf16* __restrict__ B1l, bf16* __restrict__ B1r,
                          bf16* __restrict__ B2l, bf16* __restrict__ B2r){
  int t = blockIdx.x*blockDim.x + threadIdx.x;
  const float* W; bf16* B; int K, F, Kp, i;
  if      (t <  3072){ i = t;          W = W0l; B = B0l; K=16;  F=96;  Kp=32;  }
  else if (t <  6144){ i = t-3072;     W = W0r; B = B0r; K=16;  F=96;  Kp=32;  }
  else if (t < 24576){ i = t-6144;     W = W1l; B = B1l; K=96;  F=192; Kp=96;  }
  else if (t < 43008){ i = t-24576;    W = W1r; B = B1r; K=96;  F=192; Kp=96;  }
  else if (t < 55296){ i = t-43008;    W = W2l; B = B2l; K=192; F=64;  Kp=192; }
  else if (t < 67584){ i = t-55296;    W = W2r; B = B2r; K=192; F=64;  Kp=192; }
  else return;
  int o = i / Kp, k = i % Kp;
  float v = (k < K) ? W[k*F + o] : 0.f;
  B[i] = __float2bfloat16(v);
}

// ---------------- MFMA dual linear: one wave = 16 nodes x 16 outputs ----------------
template<int K, int Kp, int Fout>
__global__ void k_linmfma(const bf16* __restrict__ x,
                          const bf16* __restrict__ Wbl, const float* __restrict__ bl,
                          const bf16* __restrict__ Wbr, const float* __restrict__ br,
                          bf16* __restrict__ yl, bf16* __restrict__ yr){
  constexpr int OT = Fout/16;
  constexpr int KSTEPS = Kp/32;
  int w = blockIdx.x*(blockDim.x>>6) + (threadIdx.x>>6);
  constexpr int MT = Nn/16;              // 1875 (exact)
  if (w >= MT * 2*OT) return;
  int mt  = w / (2*OT);
  int ot2 = w % (2*OT);
  bool isl = ot2 < OT;
  int o0 = (isl ? ot2 : ot2 - OT) * 16;
  const bf16*  Wb   = isl ? Wbl : Wbr;
  const float* bias = isl ? bl  : br;
  bf16*        y    = isl ? yl  : yr;

  int lane = threadIdx.x & 63;
  int l16  = lane & 15;
  int quad = lane >> 4;

  const bf16* arow = x  + (size_t)(mt*16 + l16)*K;
  const bf16* brow = Wb + (size_t)(o0 + l16)*Kp;

  f32x4 acc = {0.f,0.f,0.f,0.f};
  #pragma unroll
  for (int ks=0; ks<KSTEPS; ks++){
    int k0 = ks*32 + quad*8;
    short8 a;
    if (K == Kp || k0 < K) a = *(const short8*)(arow + k0);
    else                   a = short8{0,0,0,0,0,0,0,0};
    short8 b = *(const short8*)(brow + k0);
    acc = __builtin_amdgcn_mfma_f32_16x16x32_bf16(a, b, acc, 0, 0, 0);
  }

  float bo_ = bias[o0 + l16];
  #pragma unroll
  for (int r=0;r<4;r++){
    int m = mt*16 + quad*4 + r;
    y[(size_t)m*Fout + o0 + l16] = __float2bfloat16(acc[r] + bo_);
  }
}

// ---------------- per-UN-edge group processing (loads + UN independent reduce chains) ----------
template<int H, int C, int S, int UN, bool MASK>
static __device__ __forceinline__
void edge_group(const bf16* __restrict__ xl, const int* __restrict__ csr_src,
                int i, int r1, int lane,
                const float* xrv, const float* attv,
                float* acc, float* ds){
  constexpr int HC = H*C;
  float xv[UN][S], wm[UN];
  #pragma unroll
  for (int u=0;u<UN;u++){
    int iu = i + u;
    int ii = MASK ? ((iu < r1) ? iu : (r1 - 1)) : iu;   // r1>r0 always (self-loop)
    wm[u] = MASK ? ((iu < r1) ? 1.f : 0.f) : 1.f;
    int src = clampi(csr_src[ii], 0, Nn-1);
    const bf16* row = xl + (size_t)src*HC;
    #pragma unroll
    for (int s=0;s<S;s++){
      int idx = lane + 64*s;
      xv[u][s] = (idx<HC) ? b2f(row[idx]) : 0.f;
    }
  }
  #pragma unroll
  for (int u=0;u<UN;u++){
    float t[S];
    #pragma unroll
    for (int s=0;s<S;s++){
      float v = xv[u][s] + xrv[s];
      v = (v > 0.f) ? v : 0.2f*v;          // leaky_relu 0.2
      t[s] = attv[s]*v;
    }
    float p[S];
    if constexpr (H==3 && C==32){
      float a = rw32(t[0]);                 // low: head0, high: head1
      float b = rw32(t[1]);                 // low: head2
      p[0] = __expf(a);
      p[1] = __expf(b);
    } else if constexpr (H==2 && C==96){
      bool low = lane < 32;
      float z0 = t[0] + (low ? t[1] : 0.f);
      float z1 = t[2] + (low ? 0.f : t[1]);
      float h0 = rw64(z0);
      float h1 = rw64(z1);
      float e0 = __expf(h0), e1 = __expf(h1);
      p[0] = e0;
      p[1] = low ? e0 : e1;
      p[2] = e1;
    } else {                                // H==1, C==64
      p[0] = __expf(rw64(t[0]));
    }
    #pragma unroll
    for (int s=0;s<S;s++){
      float pw = MASK ? p[s]*wm[u] : p[s];
      acc[s] += pw*xv[u][s];
      ds[s]  += pw;
    }
  }
}

// ---------------- FUSED attention: 1024-thread blocks (16 waves) for CU fill ----------------
template<int H, int C>
__global__ __launch_bounds__(1024)
void k_fused(const bf16* __restrict__ xl, const bf16* __restrict__ xr,
             const int* __restrict__ csr_src, const int* __restrict__ row_start,
             const float* __restrict__ att, const float* __restrict__ bo,
             bf16* __restrict__ y){
  constexpr int HC = H*C;
  constexpr int S = (HC + 63)/64;
  int n = blockIdx.x*(blockDim.x>>6) + (threadIdx.x>>6);
  if (n >= Nn) return;
  int lane = threadIdx.x & 63;
  int r0 = clampi(row_start[n],   0, EP);
  int r1 = clampi(row_start[n+1], 0, EP);

  float xrv[S], attv[S];
  #pragma unroll
  for (int s=0;s<S;s++){
    int idx = lane + 64*s;
    xrv[s]  = (idx<HC) ? b2f(xr[(size_t)n*HC + idx]) : 0.f;
    attv[s] = (idx<HC) ? att[idx] : 0.f;
  }

  float acc[S], ds[S];
  #pragma unroll
  for (int s=0;s<S;s++){ acc[s]=0.f; ds[s]=0.f; }

  int i = r0;
  for (; i + 8 <= r1; i += 8)
    edge_group<H,C,S,8,false>(xl, csr_src, i, r1, lane, xrv, attv, acc, ds);
  for (; i < r1; i += 4)
    edge_group<H,C,S,4,true>(xl, csr_src, i, r1, lane, xrv, attv, acc, ds);

  #pragma unroll
  for (int s=0;s<S;s++){
    int idx = lane + 64*s;
    if (idx < HC)
      y[(size_t)n*HC + idx] = __float2bfloat16(acc[s]/fmaxf(ds[s], 1e-30f) + bo[idx]);
  }
}

// ---------------- mean pool + classifier head fused: one block per graph ----------------
__global__ void k_poolhead(const bf16* __restrict__ x, const int* __restrict__ batch,
                           const float* __restrict__ demo,
                           const float* __restrict__ Wc1, const float* __restrict__ bc1,
                           const float* __restrict__ Wc2, const float* __restrict__ bc2,
                           float* __restrict__ out){
  __shared__ float sh[4][64];
  __shared__ float h0[69];
  __shared__ float h1[32];
  int g = blockIdx.x;
  int t = threadIdx.x;          // 256 threads = 4 waves
  int c = t & 63;
  int w = t >> 6;
  // node range of graph g (batch sorted)
  int a = 0, b = Nn;
  while (a < b){ int m = (a+b)>>1; if (clampi(batch[m],0,Gg-1) < g) a = m+1; else b = m; }
  int lo = a;
  b = Nn;
  while (a < b){ int m = (a+b)>>1; if (clampi(batch[m],0,Gg-1) <= g) a = m+1; else b = m; }
  int hi = a;

  float s = 0.f;
  for (int n = lo + w; n < hi; n += 4)
    s += b2f(x[(size_t)n*64 + c]);
  sh[w][c] = s;
  __syncthreads();
  float invc = 1.f / fmaxf((float)(hi - lo), 1.f);
  if (t < 64) h0[t] = (sh[0][t] + sh[1][t] + sh[2][t] + sh[3][t]) * invc;
  else if (t < 69) h0[t] = demo[g*5 + (t - 64)];
  __syncthreads();
  if (t < 32){
    float v = bc1[t];
    for (int k=0;k<69;k++) v += h0[k]*Wc1[k*32 + t];
    h1[t] = fmaxf(v, 0.f);
  }
  __syncthreads();
  if (t < 2){
    float v = bc2[t];
    for (int k=0;k<32;k++) v += h1[k]*Wc2[k*2 + t];
    out[g*2 + t] = v;
  }
}

extern "C" void kernel_launch(void* const* d_in, const int* in_sizes, int n_in,
                              void* d_out, int out_size, void* d_ws, size_t ws_size,
                              hipStream_t stream) {
  const float* emb  = (const float*)d_in[0];
  const float* Wl0  = (const float*)d_in[1];
  const float* bl0  = (const float*)d_in[2];
  const float* Wr0  = (const float*)d_in[3];
  const float* br0  = (const float*)d_in[4];
  const float* att0 = (const float*)d_in[5];
  const float* bo0  = (const float*)d_in[6];
  const float* Wl1  = (const float*)d_in[7];
  const float* bl1  = (const float*)d_in[8];
  const float* Wr1  = (const float*)d_in[9];
  const float* br1  = (const float*)d_in[10];
  const float* att1 = (const float*)d_in[11];
  const float* bo1  = (const float*)d_in[12];
  const float* Wl2  = (const float*)d_in[13];
  const float* bl2  = (const float*)d_in[14];
  const float* Wr2  = (const float*)d_in[15];
  const float* br2  = (const float*)d_in[16];
  const float* att2 = (const float*)d_in[17];
  const float* bo2  = (const float*)d_in[18];
  const float* Wc1  = (const float*)d_in[19];
  const float* bc1  = (const float*)d_in[20];
  const float* Wc2  = (const float*)d_in[21];
  const float* bc2  = (const float*)d_in[22];
  const float* demo = (const float*)d_in[23];
  const int* node_ids = (const int*)d_in[24];
  const int* ei       = (const int*)d_in[25];
  const int* batch    = (const int*)d_in[26];
  float* out = (float*)d_out;

  // ---- sentinel 4000: input ordering/sizes ----
  bool ok = (n_in == 27) && (out_size == Gg*2)
         && (in_sizes[0]  == Vv*16) && (in_sizes[1]  == 16*96)
         && (in_sizes[7]  == 96*192) && (in_sizes[13] == 192*64)
         && (in_sizes[19] == 69*32) && (in_sizes[23] == Gg*5)
         && (in_sizes[24] == Nn) && (in_sizes[25] == 2*E0) && (in_sizes[26] == Nn);
  if (!ok){ k_flag<<<1, 256, 0, stream>>>(out, 4000.f); return; }

  // ---- workspace layout (sentinel 5000 if too small) ----
  size_t need = 0;
  auto plan = [&](size_t bytes){ size_t r = need; need += (bytes + 255) & ~(size_t)255; return r; };
  size_t o_x      = plan((size_t)Nn*192*2);   // bf16 node features
  size_t o_xl     = plan((size_t)Nn*192*2);   // bf16 staging
  size_t o_xr     = plan((size_t)Nn*192*2);   // bf16 staging
  size_t o_counts = plan((size_t)Nn*4);
  size_t o_cursor = plan((size_t)Nn*4);
  size_t o_rs     = plan((size_t)(Nn+1)*4);
  size_t o_csrs   = plan((size_t)EP*4);
  size_t o_wb0l   = plan((size_t)96*32*2);
  size_t o_wb0r   = plan((size_t)96*32*2);
  size_t o_wb1l   = plan((size_t)192*96*2);
  size_t o_wb1r   = plan((size_t)192*96*2);
  size_t o_wb2l   = plan((size_t)64*192*2);
  size_t o_wb2r   = plan((size_t)64*192*2);
  if (need > ws_size){ k_flag<<<1, 256, 0, stream>>>(out, 5000.f); return; }

  char* p = (char*)d_ws;
  bf16*  x      = (bf16*) (p + o_x);
  bf16*  xl     = (bf16*) (p + o_xl);
  bf16*  xr     = (bf16*) (p + o_xr);
  int*   counts = (int*)  (p + o_counts);
  int*   cursor = (int*)  (p + o_cursor);
  int*   row_start = (int*)(p + o_rs);
  int*   csr_src = (int*) (p + o_csrs);
  bf16*  wb0l   = (bf16*) (p + o_wb0l);
  bf16*  wb0r   = (bf16*) (p + o_wb0r);
  bf16*  wb1l   = (bf16*) (p + o_wb1l);
  bf16*  wb1r   = (bf16*) (p + o_wb1r);
  bf16*  wb2l   = (bf16*) (p + o_wb2l);
  bf16*  wb2r   = (bf16*) (p + o_wb2r);

  // ---- CSR build (once; shared by all 3 layers) ----
  k_zero2<<<(Nn+255)/256, 256, 0, stream>>>(counts, cursor);
  k_count<<<(EP+255)/256, 256, 0, stream>>>(ei, counts);
  k_scan<<<1, 256, 0, stream>>>(counts, row_start);
  k_fill<<<(EP+255)/256, 256, 0, stream>>>(ei, row_start, cursor, csr_src);

  // ---- pack all weights (one launch) + gather x0 ----
  k_packAll<<<(67584+255)/256, 256, 0, stream>>>(Wl0, Wr0, Wl1, Wr1, Wl2, Wr2,
                                                 wb0l, wb0r, wb1l, wb1r, wb2l, wb2r);
  k_gather<<<(Nn*16+255)/256, 256, 0, stream>>>(emb, node_ids, x);

  constexpr int MT = Nn/16;  // 1875
  int fgrid = (Nn + 15)/16;  // 16 nodes per 1024-thread block

  // ---------- layer 0: Fin=16 (pad 32), H=3, C=32 ----------
  k_linmfma<16,32,96><<<(MT*12+3)/4, 256, 0, stream>>>(x, wb0l, bl0, wb0r, br0, xl, xr);
  k_fused<3,32><<<fgrid, 1024, 0, stream>>>(xl, xr, csr_src, row_start, att0, bo0, x);

  // ---------- layer 1: Fin=96, H=2, C=96 ----------
  k_linmfma<96,96,192><<<(MT*24+3)/4, 256, 0, stream>>>(x, wb1l, bl1, wb1r, br1, xl, xr);
  k_fused<2,96><<<fgrid, 1024, 0, stream>>>(xl, xr, csr_src, row_start, att1, bo1, x);

  // ---------- layer 2: Fin=192, H=1, C=64 ----------
  k_linmfma<192,192,64><<<(MT*8+3)/4, 256, 0, stream>>>(x, wb2l, bl2, wb2r, br2, xl, xr);
  k_fused<1,64><<<fgrid, 1024, 0, stream>>>(xl, xr, csr_src, row_start, att2, bo2, x);

  // ---------- fused mean pool + head ----------
  k_poolhead<<<Gg, 256, 0, stream>>>(x, batch, demo, Wc1, bc1, Wc2, bc2, out);
}

// Round 27
// 496.966 us; speedup vs baseline: 1.1182x; 1.1182x over previous
//
#include <hip/hip_runtime.h>
#include <hip/hip_bf16.h>

typedef __hip_bfloat16 bf16;
typedef __attribute__((ext_vector_type(8))) short short8;
typedef __attribute__((ext_vector_type(4))) float f32x4;

static __device__ __forceinline__ float b2f(bf16 v){ return __bfloat162float(v); }
static __device__ __forceinline__ int clampi(int v, int lo, int hi){
  return v < lo ? lo : (v > hi ? hi : v);
}
static __device__ __forceinline__ float rw32(float v){
  #pragma unroll
  for (int m=16;m>=1;m>>=1) v += __shfl_xor(v,m,64);
  return v;
}
static __device__ __forceinline__ float rw64(float v){
  #pragma unroll
  for (int m=32;m>=1;m>>=1) v += __shfl_xor(v,m,64);
  return v;
}

constexpr int Nn = 30000;   // nodes
constexpr int E0 = 480000;  // edges (no self loops)
constexpr int EP = E0 + Nn; // edges incl self loops = 510000
constexpr int Gg = 128;     // graphs
constexpr int Vv = 10000;   // vocab size of emb

// ---------------- diagnostic flag (fp32 out) ----------------
__global__ void k_flag(float* __restrict__ out, float v){
  int t = blockIdx.x*blockDim.x + threadIdx.x;
  if (t < Gg*2) out[t] = v;
}

// ---------------- zero both CSR scratch arrays in one launch ----------------
__global__ void k_zero2(int* __restrict__ counts, int* __restrict__ cursor){
  int t = blockIdx.x*blockDim.x + threadIdx.x;
  if (t < Nn){ counts[t] = 0; cursor[t] = 0; }
}

// ---------------- CSR build (by dst) ----------------
__global__ void k_count(const int* __restrict__ ei, int* __restrict__ counts){
  int e = blockIdx.x*blockDim.x + threadIdx.x;
  if (e >= EP) return;
  int dst = (e < E0) ? clampi(ei[E0 + e], 0, Nn-1) : (e - E0);
  atomicAdd(&counts[dst], 1);
}

__global__ void k_scan(const int* __restrict__ counts, int* __restrict__ row_start){
  __shared__ int s[256];
  constexpr int CH = (Nn + 255) / 256;  // 118
  int tid = threadIdx.x;
  int base = tid*CH;
  int t_sum = 0;
  for (int j=0;j<CH;j++){ int i = base+j; if (i<Nn) t_sum += counts[i]; }
  s[tid] = t_sum; __syncthreads();
  for (int off=1; off<256; off<<=1){
    int v = (tid>=off) ? s[tid-off] : 0;
    __syncthreads();
    s[tid] += v; __syncthreads();
  }
  int run = s[tid] - t_sum; // exclusive prefix
  for (int j=0;j<CH;j++){ int i = base+j; if (i<Nn){ row_start[i] = run; run += counts[i]; } }
  if (tid == 255) row_start[Nn] = s[255];
}

__global__ void k_fill(const int* __restrict__ ei, const int* __restrict__ row_start,
                       int* __restrict__ cursor, int* __restrict__ csr_src){
  int e = blockIdx.x*blockDim.x + threadIdx.x;
  if (e >= EP) return;
  int src = (e < E0) ? clampi(ei[e],      0, Nn-1) : (e - E0);
  int dst = (e < E0) ? clampi(ei[E0 + e], 0, Nn-1) : (e - E0);
  int pos = atomicAdd(&cursor[dst], 1);
  int i = row_start[dst] + pos;
  if (i < 0 || i >= EP) return;
  csr_src[i] = src;
}

// ---------------- embedding gather (emb fp32 -> x bf16) ----------------
__global__ void k_gather(const float* __restrict__ emb, const int* __restrict__ ids,
                         bf16* __restrict__ x){
  int t = blockIdx.x*blockDim.x + threadIdx.x;
  if (t >= Nn*16) return;
  int n = t >> 4, c = t & 15;
  int id = clampi(ids[n], 0, Vv-1);
  x[t] = __float2bfloat16(emb[id*16 + c]);
}

// ---------------- pack ALL six W [K][F] fp32 -> Wb [F][Kp] bf16 in one launch ----------------
__global__ void k_packAll(const float* __restrict__ W0l, const float* __restrict__ W0r,
                          const float* __restrict__ W1l, const float* __restrict__ W1r,
                          const float* __restrict__ W2l, const float* __restrict__ W2r,
                          bf16* __restrict__ B0l, bf16* __restrict__ B0r,
                          bf16* __restrict__ B1l, bf16* __restrict__ B1r,
                          bf16* __restrict__ B2l, bf16* __restrict__ B2r){
  int t = blockIdx.x*blockDim.x + threadIdx.x;
  const float* W; bf16* B; int K, F, Kp, i;
  if      (t <  3072){ i = t;          W = W0l; B = B0l; K=16;  F=96;  Kp=32;  }
  else if (t <  6144){ i = t-3072;     W = W0r; B = B0r; K=16;  F=96;  Kp=32;  }
  else if (t < 24576){ i = t-6144;     W = W1l; B = B1l; K=96;  F=192; Kp=96;  }
  else if (t < 43008){ i = t-24576;    W = W1r; B = B1r; K=96;  F=192; Kp=96;  }
  else if (t < 55296){ i = t-43008;    W = W2l; B = B2l; K=192; F=64;  Kp=192; }
  else if (t < 67584){ i = t-55296;    W = W2r; B = B2r; K=192; F=64;  Kp=192; }
  else return;
  int o = i / Kp, k = i % Kp;
  float v = (k < K) ? W[k*F + o] : 0.f;
  B[i] = __float2bfloat16(v);
}

// ---------------- MFMA dual linear: one wave = 16 nodes x 16 outputs ----------------
template<int K, int Kp, int Fout>
__global__ void k_linmfma(const bf16* __restrict__ x,
                          const bf16* __restrict__ Wbl, const float* __restrict__ bl,
                          const bf16* __restrict__ Wbr, const float* __restrict__ br,
                          bf16* __restrict__ yl, bf16* __restrict__ yr){
  constexpr int OT = Fout/16;
  constexpr int KSTEPS = Kp/32;
  int w = blockIdx.x*(blockDim.x>>6) + (threadIdx.x>>6);
  constexpr int MT = Nn/16;              // 1875 (exact)
  if (w >= MT * 2*OT) return;
  int mt  = w / (2*OT);
  int ot2 = w % (2*OT);
  bool isl = ot2 < OT;
  int o0 = (isl ? ot2 : ot2 - OT) * 16;
  const bf16*  Wb   = isl ? Wbl : Wbr;
  const float* bias = isl ? bl  : br;
  bf16*        y    = isl ? yl  : yr;

  int lane = threadIdx.x & 63;
  int l16  = lane & 15;
  int quad = lane >> 4;

  const bf16* arow = x  + (size_t)(mt*16 + l16)*K;
  const bf16* brow = Wb + (size_t)(o0 + l16)*Kp;

  f32x4 acc = {0.f,0.f,0.f,0.f};
  #pragma unroll
  for (int ks=0; ks<KSTEPS; ks++){
    int k0 = ks*32 + quad*8;
    short8 a;
    if (K == Kp || k0 < K) a = *(const short8*)(arow + k0);
    else                   a = short8{0,0,0,0,0,0,0,0};
    short8 b = *(const short8*)(brow + k0);
    acc = __builtin_amdgcn_mfma_f32_16x16x32_bf16(a, b, acc, 0, 0, 0);
  }

  float bo_ = bias[o0 + l16];
  #pragma unroll
  for (int r=0;r<4;r++){
    int m = mt*16 + quad*4 + r;
    y[(size_t)m*Fout + o0 + l16] = __float2bfloat16(acc[r] + bo_);
  }
}

// ---------------- per-UN-edge group processing (loads + UN independent reduce chains) ----------
template<int H, int C, int S, int UN, bool MASK>
static __device__ __forceinline__
void edge_group(const bf16* __restrict__ xl, const int* __restrict__ csr_src,
                int i, int r1, int lane,
                const float* xrv, const float* attv,
                float* acc, float* ds){
  constexpr int HC = H*C;
  float xv[UN][S], wm[UN];
  #pragma unroll
  for (int u=0;u<UN;u++){
    int iu = i + u;
    int ii = MASK ? ((iu < r1) ? iu : (r1 - 1)) : iu;   // r1>r0 always (self-loop)
    wm[u] = MASK ? ((iu < r1) ? 1.f : 0.f) : 1.f;
    int src = clampi(csr_src[ii], 0, Nn-1);
    const bf16* row = xl + (size_t)src*HC;
    #pragma unroll
    for (int s=0;s<S;s++){
      int idx = lane + 64*s;
      xv[u][s] = (idx<HC) ? b2f(row[idx]) : 0.f;
    }
  }
  #pragma unroll
  for (int u=0;u<UN;u++){
    float t[S];
    #pragma unroll
    for (int s=0;s<S;s++){
      float v = xv[u][s] + xrv[s];
      v = (v > 0.f) ? v : 0.2f*v;          // leaky_relu 0.2
      t[s] = attv[s]*v;
    }
    float p[S];
    if constexpr (H==3 && C==32){
      float a = rw32(t[0]);                 // low: head0, high: head1
      float b = rw32(t[1]);                 // low: head2
      p[0] = __expf(a);
      p[1] = __expf(b);
    } else if constexpr (H==2 && C==96){
      bool low = lane < 32;
      float z0 = t[0] + (low ? t[1] : 0.f);
      float z1 = t[2] + (low ? 0.f : t[1]);
      float h0 = rw64(z0);
      float h1 = rw64(z1);
      float e0 = __expf(h0), e1 = __expf(h1);
      p[0] = e0;
      p[1] = low ? e0 : e1;
      p[2] = e1;
    } else {                                // H==1, C==64
      p[0] = __expf(rw64(t[0]));
    }
    #pragma unroll
    for (int s=0;s<S;s++){
      float pw = MASK ? p[s]*wm[u] : p[s];
      acc[s] += pw*xv[u][s];
      ds[s]  += pw;
    }
  }
}

// ---------------- FUSED attention: 256-thread blocks (proven best scheduling granularity) ------
template<int H, int C>
__global__ void k_fused(const bf16* __restrict__ xl, const bf16* __restrict__ xr,
                        const int* __restrict__ csr_src, const int* __restrict__ row_start,
                        const float* __restrict__ att, const float* __restrict__ bo,
                        bf16* __restrict__ y){
  constexpr int HC = H*C;
  constexpr int S = (HC + 63)/64;
  int n = blockIdx.x*(blockDim.x>>6) + (threadIdx.x>>6);
  if (n >= Nn) return;
  int lane = threadIdx.x & 63;
  int r0 = clampi(row_start[n],   0, EP);
  int r1 = clampi(row_start[n+1], 0, EP);

  float xrv[S], attv[S];
  #pragma unroll
  for (int s=0;s<S;s++){
    int idx = lane + 64*s;
    xrv[s]  = (idx<HC) ? b2f(xr[(size_t)n*HC + idx]) : 0.f;
    attv[s] = (idx<HC) ? att[idx] : 0.f;
  }

  float acc[S], ds[S];
  #pragma unroll
  for (int s=0;s<S;s++){ acc[s]=0.f; ds[s]=0.f; }

  int i = r0;
  for (; i + 8 <= r1; i += 8)
    edge_group<H,C,S,8,false>(xl, csr_src, i, r1, lane, xrv, attv, acc, ds);
  for (; i < r1; i += 4)
    edge_group<H,C,S,4,true>(xl, csr_src, i, r1, lane, xrv, attv, acc, ds);

  #pragma unroll
  for (int s=0;s<S;s++){
    int idx = lane + 64*s;
    if (idx < HC)
      y[(size_t)n*HC + idx] = __float2bfloat16(acc[s]/fmaxf(ds[s], 1e-30f) + bo[idx]);
  }
}

// ---------------- mean pool + classifier head fused: one block per graph ----------------
__global__ void k_poolhead(const bf16* __restrict__ x, const int* __restrict__ batch,
                           const float* __restrict__ demo,
                           const float* __restrict__ Wc1, const float* __restrict__ bc1,
                           const float* __restrict__ Wc2, const float* __restrict__ bc2,
                           float* __restrict__ out){
  __shared__ float sh[4][64];
  __shared__ float h0[69];
  __shared__ float h1[32];
  int g = blockIdx.x;
  int t = threadIdx.x;          // 256 threads = 4 waves
  int c = t & 63;
  int w = t >> 6;
  int a = 0, b = Nn;
  while (a < b){ int m = (a+b)>>1; if (clampi(batch[m],0,Gg-1) < g) a = m+1; else b = m; }
  int lo = a;
  b = Nn;
  while (a < b){ int m = (a+b)>>1; if (clampi(batch[m],0,Gg-1) <= g) a = m+1; else b = m; }
  int hi = a;

  float s = 0.f;
  for (int n = lo + w; n < hi; n += 4)
    s += b2f(x[(size_t)n*64 + c]);
  sh[w][c] = s;
  __syncthreads();
  float invc = 1.f / fmaxf((float)(hi - lo), 1.f);
  if (t < 64) h0[t] = (sh[0][t] + sh[1][t] + sh[2][t] + sh[3][t]) * invc;
  else if (t < 69) h0[t] = demo[g*5 + (t - 64)];
  __syncthreads();
  if (t < 32){
    float v = bc1[t];
    for (int k=0;k<69;k++) v += h0[k]*Wc1[k*32 + t];
    h1[t] = fmaxf(v, 0.f);
  }
  __syncthreads();
  if (t < 2){
    float v = bc2[t];
    for (int k=0;k<32;k++) v += h1[k]*Wc2[k*2 + t];
    out[g*2 + t] = v;
  }
}

extern "C" void kernel_launch(void* const* d_in, const int* in_sizes, int n_in,
                              void* d_out, int out_size, void* d_ws, size_t ws_size,
                              hipStream_t stream) {
  const float* emb  = (const float*)d_in[0];
  const float* Wl0  = (const float*)d_in[1];
  const float* bl0  = (const float*)d_in[2];
  const float* Wr0  = (const float*)d_in[3];
  const float* br0  = (const float*)d_in[4];
  const float* att0 = (const float*)d_in[5];
  const float* bo0  = (const float*)d_in[6];
  const float* Wl1  = (const float*)d_in[7];
  const float* bl1  = (const float*)d_in[8];
  const float* Wr1  = (const float*)d_in[9];
  const float* br1  = (const float*)d_in[10];
  const float* att1 = (const float*)d_in[11];
  const float* bo1  = (const float*)d_in[12];
  const float* Wl2  = (const float*)d_in[13];
  const float* bl2  = (const float*)d_in[14];
  const float* Wr2  = (const float*)d_in[15];
  const float* br2  = (const float*)d_in[16];
  const float* att2 = (const float*)d_in[17];
  const float* bo2  = (const float*)d_in[18];
  const float* Wc1  = (const float*)d_in[19];
  const float* bc1  = (const float*)d_in[20];
  const float* Wc2  = (const float*)d_in[21];
  const float* bc2  = (const float*)d_in[22];
  const float* demo = (const float*)d_in[23];
  const int* node_ids = (const int*)d_in[24];
  const int* ei       = (const int*)d_in[25];
  const int* batch    = (const int*)d_in[26];
  float* out = (float*)d_out;

  // ---- sentinel 4000: input ordering/sizes ----
  bool ok = (n_in == 27) && (out_size == Gg*2)
         && (in_sizes[0]  == Vv*16) && (in_sizes[1]  == 16*96)
         && (in_sizes[7]  == 96*192) && (in_sizes[13] == 192*64)
         && (in_sizes[19] == 69*32) && (in_sizes[23] == Gg*5)
         && (in_sizes[24] == Nn) && (in_sizes[25] == 2*E0) && (in_sizes[26] == Nn);
  if (!ok){ k_flag<<<1, 256, 0, stream>>>(out, 4000.f); return; }

  // ---- workspace layout (sentinel 5000 if too small) ----
  size_t need = 0;
  auto plan = [&](size_t bytes){ size_t r = need; need += (bytes + 255) & ~(size_t)255; return r; };
  size_t o_x      = plan((size_t)Nn*192*2);   // bf16 node features
  size_t o_xl     = plan((size_t)Nn*192*2);   // bf16 staging
  size_t o_xr     = plan((size_t)Nn*192*2);   // bf16 staging
  size_t o_counts = plan((size_t)Nn*4);
  size_t o_cursor = plan((size_t)Nn*4);
  size_t o_rs     = plan((size_t)(Nn+1)*4);
  size_t o_csrs   = plan((size_t)EP*4);
  size_t o_wb0l   = plan((size_t)96*32*2);
  size_t o_wb0r   = plan((size_t)96*32*2);
  size_t o_wb1l   = plan((size_t)192*96*2);
  size_t o_wb1r   = plan((size_t)192*96*2);
  size_t o_wb2l   = plan((size_t)64*192*2);
  size_t o_wb2r   = plan((size_t)64*192*2);
  if (need > ws_size){ k_flag<<<1, 256, 0, stream>>>(out, 5000.f); return; }

  char* p = (char*)d_ws;
  bf16*  x      = (bf16*) (p + o_x);
  bf16*  xl     = (bf16*) (p + o_xl);
  bf16*  xr     = (bf16*) (p + o_xr);
  int*   counts = (int*)  (p + o_counts);
  int*   cursor = (int*)  (p + o_cursor);
  int*   row_start = (int*)(p + o_rs);
  int*   csr_src = (int*) (p + o_csrs);
  bf16*  wb0l   = (bf16*) (p + o_wb0l);
  bf16*  wb0r   = (bf16*) (p + o_wb0r);
  bf16*  wb1l   = (bf16*) (p + o_wb1l);
  bf16*  wb1r   = (bf16*) (p + o_wb1r);
  bf16*  wb2l   = (bf16*) (p + o_wb2l);
  bf16*  wb2r   = (bf16*) (p + o_wb2r);

  // ---- CSR build (once; shared by all 3 layers) ----
  k_zero2<<<(Nn+255)/256, 256, 0, stream>>>(counts, cursor);
  k_count<<<(EP+255)/256, 256, 0, stream>>>(ei, counts);
  k_scan<<<1, 256, 0, stream>>>(counts, row_start);
  k_fill<<<(EP+255)/256, 256, 0, stream>>>(ei, row_start, cursor, csr_src);

  // ---- pack all weights (one launch) + gather x0 ----
  k_packAll<<<(67584+255)/256, 256, 0, stream>>>(Wl0, Wr0, Wl1, Wr1, Wl2, Wr2,
                                                 wb0l, wb0r, wb1l, wb1r, wb2l, wb2r);
  k_gather<<<(Nn*16+255)/256, 256, 0, stream>>>(emb, node_ids, x);

  constexpr int MT = Nn/16;  // 1875
  int wgrid = (Nn+3)/4;      // 4 waves/block, 1 node per wave

  // ---------- layer 0: Fin=16 (pad 32), H=3, C=32 ----------
  k_linmfma<16,32,96><<<(MT*12+3)/4, 256, 0, stream>>>(x, wb0l, bl0, wb0r, br0, xl, xr);
  k_fused<3,32><<<wgrid, 256, 0, stream>>>(xl, xr, csr_src, row_start, att0, bo0, x);

  // ---------- layer 1: Fin=96, H=2, C=96 ----------
  k_linmfma<96,96,192><<<(MT*24+3)/4, 256, 0, stream>>>(x, wb1l, bl1, wb1r, br1, xl, xr);
  k_fused<2,96><<<wgrid, 256, 0, stream>>>(xl, xr, csr_src, row_start, att1, bo1, x);

  // ---------- layer 2: Fin=192, H=1, C=64 ----------
  k_linmfma<192,192,64><<<(MT*8+3)/4, 256, 0, stream>>>(x, wb2l, bl2, wb2r, br2, xl, xr);
  k_fused<1,64><<<wgrid, 256, 0, stream>>>(xl, xr, csr_src, row_start, att2, bo2, x);

  // ---------- fused mean pool + head ----------
  k_poolhead<<<Gg, 256, 0, stream>>>(x, batch, demo, Wc1, bc1, Wc2, bc2, out);
}

// Round 28
// 446.427 us; speedup vs baseline: 1.2448x; 1.1132x over previous
//
#include <hip/hip_runtime.h>
#include <hip/hip_bf16.h>

typedef __hip_bfloat16 bf16;
typedef __attribute__((ext_vector_type(8))) short short8;
typedef __attribute__((ext_vector_type(4))) float f32x4;

static __device__ __forceinline__ float b2f(bf16 v){ return __bfloat162float(v); }
static __device__ __forceinline__ float blo(unsigned u){ return __uint_as_float(u<<16); }
static __device__ __forceinline__ float bhi(unsigned u){ return __uint_as_float(u & 0xffff0000u); }
static __device__ __forceinline__ int clampi(int v, int lo, int hi){
  return v < lo ? lo : (v > hi ? hi : v);
}
static __device__ __forceinline__ float rw16(float v){
  #pragma unroll
  for (int m=8;m>=1;m>>=1) v += __shfl_xor(v,m,64);
  return v;
}
static __device__ __forceinline__ float rw64(float v){
  #pragma unroll
  for (int m=32;m>=1;m>>=1) v += __shfl_xor(v,m,64);
  return v;
}

constexpr int Nn = 30000;   // nodes
constexpr int E0 = 480000;  // edges (no self loops)
constexpr int EP = E0 + Nn; // edges incl self loops = 510000
constexpr int Gg = 128;     // graphs
constexpr int Vv = 10000;   // vocab size of emb

// ---------------- diagnostic flag (fp32 out) ----------------
__global__ void k_flag(float* __restrict__ out, float v){
  int t = blockIdx.x*blockDim.x + threadIdx.x;
  if (t < Gg*2) out[t] = v;
}

// ---------------- prep: zero CSR scratch + pack all W + gather emb (one launch) ----------------
__global__ void k_prep(const float* __restrict__ emb, const int* __restrict__ ids,
                       bf16* __restrict__ x,
                       int* __restrict__ counts, int* __restrict__ cursor,
                       const float* __restrict__ W0l, const float* __restrict__ W0r,
                       const float* __restrict__ W1l, const float* __restrict__ W1r,
                       const float* __restrict__ W2l, const float* __restrict__ W2r,
                       bf16* __restrict__ B0l, bf16* __restrict__ B0r,
                       bf16* __restrict__ B1l, bf16* __restrict__ B1r,
                       bf16* __restrict__ B2l, bf16* __restrict__ B2r){
  int t = blockIdx.x*blockDim.x + threadIdx.x;
  if (t < Nn){ counts[t] = 0; cursor[t] = 0; }
  if (t < 67584){
    const float* W; bf16* B; int K, F, Kp, i;
    if      (t <  3072){ i = t;       W = W0l; B = B0l; K=16;  F=96;  Kp=32;  }
    else if (t <  6144){ i = t-3072;  W = W0r; B = B0r; K=16;  F=96;  Kp=32;  }
    else if (t < 24576){ i = t-6144;  W = W1l; B = B1l; K=96;  F=192; Kp=96;  }
    else if (t < 43008){ i = t-24576; W = W1r; B = B1r; K=96;  F=192; Kp=96;  }
    else if (t < 55296){ i = t-43008; W = W2l; B = B2l; K=192; F=64;  Kp=192; }
    else               { i = t-55296; W = W2r; B = B2r; K=192; F=64;  Kp=192; }
    int o = i / Kp, k = i % Kp;
    float v = (k < K) ? W[k*F + o] : 0.f;
    B[i] = __float2bfloat16(v);
  }
  if (t < Nn*16){
    int n = t >> 4, c = t & 15;
    int id = clampi(ids[n], 0, Vv-1);
    x[t] = __float2bfloat16(emb[id*16 + c]);
  }
}

// ---------------- CSR build (by dst) ----------------
__global__ void k_count(const int* __restrict__ ei, int* __restrict__ counts){
  int e = blockIdx.x*blockDim.x + threadIdx.x;
  if (e >= EP) return;
  int dst = (e < E0) ? clampi(ei[E0 + e], 0, Nn-1) : (e - E0);
  atomicAdd(&counts[dst], 1);
}

__global__ void k_scan(const int* __restrict__ counts, int* __restrict__ row_start){
  __shared__ int s[256];
  constexpr int CH = (Nn + 255) / 256;  // 118
  int tid = threadIdx.x;
  int base = tid*CH;
  int t_sum = 0;
  for (int j=0;j<CH;j++){ int i = base+j; if (i<Nn) t_sum += counts[i]; }
  s[tid] = t_sum; __syncthreads();
  for (int off=1; off<256; off<<=1){
    int v = (tid>=off) ? s[tid-off] : 0;
    __syncthreads();
    s[tid] += v; __syncthreads();
  }
  int run = s[tid] - t_sum; // exclusive prefix
  for (int j=0;j<CH;j++){ int i = base+j; if (i<Nn){ row_start[i] = run; run += counts[i]; } }
  if (tid == 255) row_start[Nn] = s[255];
}

__global__ void k_fill(const int* __restrict__ ei, const int* __restrict__ row_start,
                       int* __restrict__ cursor, int* __restrict__ csr_src){
  int e = blockIdx.x*blockDim.x + threadIdx.x;
  if (e >= EP) return;
  int src = (e < E0) ? clampi(ei[e],      0, Nn-1) : (e - E0);
  int dst = (e < E0) ? clampi(ei[E0 + e], 0, Nn-1) : (e - E0);
  int pos = atomicAdd(&cursor[dst], 1);
  int i = row_start[dst] + pos;
  if (i < 0 || i >= EP) return;
  csr_src[i] = src;
}

// ---------------- MFMA dual linear: one wave = 16 nodes x 16 outputs ----------------
template<int K, int Kp, int Fout>
__global__ void k_linmfma(const bf16* __restrict__ x,
                          const bf16* __restrict__ Wbl, const float* __restrict__ bl,
                          const bf16* __restrict__ Wbr, const float* __restrict__ br,
                          bf16* __restrict__ yl, bf16* __restrict__ yr){
  constexpr int OT = Fout/16;
  constexpr int KSTEPS = Kp/32;
  int w = blockIdx.x*(blockDim.x>>6) + (threadIdx.x>>6);
  constexpr int MT = Nn/16;              // 1875 (exact)
  if (w >= MT * 2*OT) return;
  int mt  = w / (2*OT);
  int ot2 = w % (2*OT);
  bool isl = ot2 < OT;
  int o0 = (isl ? ot2 : ot2 - OT) * 16;
  const bf16*  Wb   = isl ? Wbl : Wbr;
  const float* bias = isl ? bl  : br;
  bf16*        y    = isl ? yl  : yr;

  int lane = threadIdx.x & 63;
  int l16  = lane & 15;
  int quad = lane >> 4;

  const bf16* arow = x  + (size_t)(mt*16 + l16)*K;
  const bf16* brow = Wb + (size_t)(o0 + l16)*Kp;

  f32x4 acc = {0.f,0.f,0.f,0.f};
  #pragma unroll
  for (int ks=0; ks<KSTEPS; ks++){
    int k0 = ks*32 + quad*8;
    short8 a;
    if (K == Kp || k0 < K) a = *(const short8*)(arow + k0);
    else                   a = short8{0,0,0,0,0,0,0,0};
    short8 b = *(const short8*)(brow + k0);
    acc = __builtin_amdgcn_mfma_f32_16x16x32_bf16(a, b, acc, 0, 0, 0);
  }

  float bo_ = bias[o0 + l16];
  #pragma unroll
  for (int r=0;r<4;r++){
    int m = mt*16 + quad*4 + r;
    y[(size_t)m*Fout + o0 + l16] = __float2bfloat16(acc[r] + bo_);
  }
}

// ================= layer 0 fused (H=3,C=32,HC=96): 2 ch/lane, rw16 head-reduce ================
template<int UN, bool MASK>
static __device__ __forceinline__
void grp0v(const bf16* __restrict__ xl, const int* __restrict__ csr_src,
           int i, int r1, int ch,
           float xr0, float xr1, float a0, float a1,
           float& acc0, float& acc1, float& ds){
  unsigned xw[UN]; float wm[UN];
  #pragma unroll
  for (int u=0;u<UN;u++){
    int iu = i+u;
    int ii = MASK ? ((iu<r1)? iu : (r1-1)) : iu;
    wm[u] = MASK ? ((iu<r1)?1.f:0.f) : 1.f;
    int src = clampi(csr_src[ii],0,Nn-1);
    xw[u] = *(const unsigned*)(xl + (size_t)src*96 + ch);
  }
  #pragma unroll
  for (int u=0;u<UN;u++){
    float c0 = blo(xw[u]), c1 = bhi(xw[u]);
    float v0 = c0+xr0; v0 = (v0>0.f)? v0 : 0.2f*v0;
    float v1 = c1+xr1; v1 = (v1>0.f)? v1 : 0.2f*v1;
    float t = a0*v0 + a1*v1;
    float hs = rw16(t);       // heads align to 16-lane groups
    float p = __expf(hs);
    if (MASK) p *= wm[u];
    acc0 += p*c0; acc1 += p*c1; ds += p;
  }
}

__global__ void k_fused0v(const bf16* __restrict__ xl, const bf16* __restrict__ xr,
                          const int* __restrict__ csr_src, const int* __restrict__ row_start,
                          const float* __restrict__ att, const float* __restrict__ bo,
                          bf16* __restrict__ y){
  int n = blockIdx.x*(blockDim.x>>6) + (threadIdx.x>>6);
  if (n >= Nn) return;
  int lane = threadIdx.x & 63;
  bool act = lane < 48;
  int ch = act ? 2*lane : 0;
  int r0 = clampi(row_start[n],0,EP), r1 = clampi(row_start[n+1],0,EP);
  unsigned xrw = *(const unsigned*)(xr + (size_t)n*96 + ch);
  float xr0 = blo(xrw), xr1 = bhi(xrw);
  float a0=0.f, a1=0.f;
  if (act){ float2 av = *(const float2*)(att + ch); a0=av.x; a1=av.y; }
  float acc0=0.f, acc1=0.f, ds=0.f;
  int i=r0;
  for (; i+8<=r1; i+=8) grp0v<8,false>(xl,csr_src,i,r1,ch,xr0,xr1,a0,a1,acc0,acc1,ds);
  for (; i<r1; i+=4)    grp0v<4,true >(xl,csr_src,i,r1,ch,xr0,xr1,a0,a1,acc0,acc1,ds);
  if (act){
    float inv = 1.f/fmaxf(ds,1e-30f);
    y[(size_t)n*96 + ch  ] = __float2bfloat16(acc0*inv + bo[ch]);
    y[(size_t)n*96 + ch+1] = __float2bfloat16(acc1*inv + bo[ch+1]);
  }
}

// ================= layer 1 fused (H=2,C=96,HC=192): 4 ch/lane, single 8B load/edge ============
template<int UN, bool MASK>
static __device__ __forceinline__
void grp1v(const bf16* __restrict__ xl, const int* __restrict__ csr_src,
           int i, int r1, int ch, int lane,
           const float* xrv, const float* av,
           float* acc, float& ds){
  uint2 xw[UN]; float wm[UN];
  #pragma unroll
  for (int u=0;u<UN;u++){
    int iu = i+u;
    int ii = MASK ? ((iu<r1)? iu : (r1-1)) : iu;
    wm[u] = MASK ? ((iu<r1)?1.f:0.f) : 1.f;
    int src = clampi(csr_src[ii],0,Nn-1);
    xw[u] = *(const uint2*)(xl + (size_t)src*192 + ch);
  }
  #pragma unroll
  for (int u=0;u<UN;u++){
    float c0 = blo(xw[u].x), c1 = bhi(xw[u].x), c2 = blo(xw[u].y), c3 = bhi(xw[u].y);
    float v0 = c0+xrv[0]; v0 = (v0>0.f)? v0 : 0.2f*v0;
    float v1 = c1+xrv[1]; v1 = (v1>0.f)? v1 : 0.2f*v1;
    float v2 = c2+xrv[2]; v2 = (v2>0.f)? v2 : 0.2f*v2;
    float v3 = c3+xrv[3]; v3 = (v3>0.f)? v3 : 0.2f*v3;
    float ts = av[0]*v0 + av[1]*v1 + av[2]*v2 + av[3]*v3;
    float z0 = (lane<24) ? ts : 0.f;
    float z1 = ts - z0;
    float h0 = rw64(z0);
    float h1 = rw64(z1);
    float p = __expf((lane<24) ? h0 : h1);
    if (MASK) p *= wm[u];
    acc[0]+=p*c0; acc[1]+=p*c1; acc[2]+=p*c2; acc[3]+=p*c3; ds+=p;
  }
}

__global__ void k_fused1v(const bf16* __restrict__ xl, const bf16* __restrict__ xr,
                          const int* __restrict__ csr_src, const int* __restrict__ row_start,
                          const float* __restrict__ att, const float* __restrict__ bo,
                          bf16* __restrict__ y){
  int n = blockIdx.x*(blockDim.x>>6) + (threadIdx.x>>6);
  if (n >= Nn) return;
  int lane = threadIdx.x & 63;
  bool act = lane < 48;
  int ch = act ? 4*lane : 0;
  int r0 = clampi(row_start[n],0,EP), r1 = clampi(row_start[n+1],0,EP);
  uint2 xrw = *(const uint2*)(xr + (size_t)n*192 + ch);
  float xrv[4] = { blo(xrw.x), bhi(xrw.x), blo(xrw.y), bhi(xrw.y) };
  float av[4] = {0.f,0.f,0.f,0.f};
  if (act){ float4 a4 = *(const float4*)(att + ch); av[0]=a4.x; av[1]=a4.y; av[2]=a4.z; av[3]=a4.w; }
  float acc[4] = {0.f,0.f,0.f,0.f};
  float ds = 0.f;
  int i=r0;
  for (; i+8<=r1; i+=8) grp1v<8,false>(xl,csr_src,i,r1,ch,lane,xrv,av,acc,ds);
  for (; i<r1; i+=4)    grp1v<4,true >(xl,csr_src,i,r1,ch,lane,xrv,av,acc,ds);
  if (act){
    float inv = 1.f/fmaxf(ds,1e-30f);
    #pragma unroll
    for (int j=0;j<4;j++)
      y[(size_t)n*192 + ch + j] = __float2bfloat16(acc[j]*inv + bo[ch+j]);
  }
}

// ================= layer 2 fused (H=1,C=64): original scalar path (already minimal) ===========
template<int UN, bool MASK>
static __device__ __forceinline__
void grp2(const bf16* __restrict__ xl, const int* __restrict__ csr_src,
          int i, int r1, int lane, float xrv, float attv,
          float& acc, float& ds){
  float xv[UN], wm[UN];
  #pragma unroll
  for (int u=0;u<UN;u++){
    int iu = i+u;
    int ii = MASK ? ((iu<r1)? iu : (r1-1)) : iu;
    wm[u] = MASK ? ((iu<r1)?1.f:0.f) : 1.f;
    int src = clampi(csr_src[ii],0,Nn-1);
    xv[u] = b2f(xl[(size_t)src*64 + lane]);
  }
  #pragma unroll
  for (int u=0;u<UN;u++){
    float v = xv[u] + xrv;
    v = (v>0.f)? v : 0.2f*v;
    float p = __expf(rw64(attv*v));
    if (MASK) p *= wm[u];
    acc += p*xv[u]; ds += p;
  }
}

__global__ void k_fused2(const bf16* __restrict__ xl, const bf16* __restrict__ xr,
                         const int* __restrict__ csr_src, const int* __restrict__ row_start,
                         const float* __restrict__ att, const float* __restrict__ bo,
                         bf16* __restrict__ y){
  int n = blockIdx.x*(blockDim.x>>6) + (threadIdx.x>>6);
  if (n >= Nn) return;
  int lane = threadIdx.x & 63;
  int r0 = clampi(row_start[n],0,EP), r1 = clampi(row_start[n+1],0,EP);
  float xrv  = b2f(xr[(size_t)n*64 + lane]);
  float attv = att[lane];
  float acc = 0.f, ds = 0.f;
  int i=r0;
  for (; i+8<=r1; i+=8) grp2<8,false>(xl,csr_src,i,r1,lane,xrv,attv,acc,ds);
  for (; i<r1; i+=4)    grp2<4,true >(xl,csr_src,i,r1,lane,xrv,attv,acc,ds);
  y[(size_t)n*64 + lane] = __float2bfloat16(acc/fmaxf(ds,1e-30f) + bo[lane]);
}

// ---------------- mean pool + classifier head fused: one block per graph ----------------
__global__ void k_poolhead(const bf16* __restrict__ x, const int* __restrict__ batch,
                           const float* __restrict__ demo,
                           const float* __restrict__ Wc1, const float* __restrict__ bc1,
                           const float* __restrict__ Wc2, const float* __restrict__ bc2,
                           float* __restrict__ out){
  __shared__ float sh[4][64];
  __shared__ float h0[69];
  __shared__ float h1[32];
  int g = blockIdx.x;
  int t = threadIdx.x;          // 256 threads = 4 waves
  int c = t & 63;
  int w = t >> 6;
  int a = 0, b = Nn;
  while (a < b){ int m = (a+b)>>1; if (clampi(batch[m],0,Gg-1) < g) a = m+1; else b = m; }
  int lo = a;
  b = Nn;
  while (a < b){ int m = (a+b)>>1; if (clampi(batch[m],0,Gg-1) <= g) a = m+1; else b = m; }
  int hi = a;

  float s = 0.f;
  for (int n = lo + w; n < hi; n += 4)
    s += b2f(x[(size_t)n*64 + c]);
  sh[w][c] = s;
  __syncthreads();
  float invc = 1.f / fmaxf((float)(hi - lo), 1.f);
  if (t < 64) h0[t] = (sh[0][t] + sh[1][t] + sh[2][t] + sh[3][t]) * invc;
  else if (t < 69) h0[t] = demo[g*5 + (t - 64)];
  __syncthreads();
  if (t < 32){
    float v = bc1[t];
    for (int k=0;k<69;k++) v += h0[k]*Wc1[k*32 + t];
    h1[t] = fmaxf(v, 0.f);
  }
  __syncthreads();
  if (t < 2){
    float v = bc2[t];
    for (int k=0;k<32;k++) v += h1[k]*Wc2[k*2 + t];
    out[g*2 + t] = v;
  }
}

extern "C" void kernel_launch(void* const* d_in, const int* in_sizes, int n_in,
                              void* d_out, int out_size, void* d_ws, size_t ws_size,
                              hipStream_t stream) {
  const float* emb  = (const float*)d_in[0];
  const float* Wl0  = (const float*)d_in[1];
  const float* bl0  = (const float*)d_in[2];
  const float* Wr0  = (const float*)d_in[3];
  const float* br0  = (const float*)d_in[4];
  const float* att0 = (const float*)d_in[5];
  const float* bo0  = (const float*)d_in[6];
  const float* Wl1  = (const float*)d_in[7];
  const float* bl1  = (const float*)d_in[8];
  const float* Wr1  = (const float*)d_in[9];
  const float* br1  = (const float*)d_in[10];
  const float* att1 = (const float*)d_in[11];
  const float* bo1  = (const float*)d_in[12];
  const float* Wl2  = (const float*)d_in[13];
  const float* bl2  = (const float*)d_in[14];
  const float* Wr2  = (const float*)d_in[15];
  const float* br2  = (const float*)d_in[16];
  const float* att2 = (const float*)d_in[17];
  const float* bo2  = (const float*)d_in[18];
  const float* Wc1  = (const float*)d_in[19];
  const float* bc1  = (const float*)d_in[20];
  const float* Wc2  = (const float*)d_in[21];
  const float* bc2  = (const float*)d_in[22];
  const float* demo = (const float*)d_in[23];
  const int* node_ids = (const int*)d_in[24];
  const int* ei       = (const int*)d_in[25];
  const int* batch    = (const int*)d_in[26];
  float* out = (float*)d_out;

  // ---- sentinel 4000: input ordering/sizes ----
  bool ok = (n_in == 27) && (out_size == Gg*2)
         && (in_sizes[0]  == Vv*16) && (in_sizes[1]  == 16*96)
         && (in_sizes[7]  == 96*192) && (in_sizes[13] == 192*64)
         && (in_sizes[19] == 69*32) && (in_sizes[23] == Gg*5)
         && (in_sizes[24] == Nn) && (in_sizes[25] == 2*E0) && (in_sizes[26] == Nn);
  if (!ok){ k_flag<<<1, 256, 0, stream>>>(out, 4000.f); return; }

  // ---- workspace layout (sentinel 5000 if too small) ----
  size_t need = 0;
  auto plan = [&](size_t bytes){ size_t r = need; need += (bytes + 255) & ~(size_t)255; return r; };
  size_t o_x      = plan((size_t)Nn*192*2);   // bf16 node features
  size_t o_xl     = plan((size_t)Nn*192*2);   // bf16 staging
  size_t o_xr     = plan((size_t)Nn*192*2);   // bf16 staging
  size_t o_counts = plan((size_t)Nn*4);
  size_t o_cursor = plan((size_t)Nn*4);
  size_t o_rs     = plan((size_t)(Nn+1)*4);
  size_t o_csrs   = plan((size_t)EP*4);
  size_t o_wb0l   = plan((size_t)96*32*2);
  size_t o_wb0r   = plan((size_t)96*32*2);
  size_t o_wb1l   = plan((size_t)192*96*2);
  size_t o_wb1r   = plan((size_t)192*96*2);
  size_t o_wb2l   = plan((size_t)64*192*2);
  size_t o_wb2r   = plan((size_t)64*192*2);
  if (need > ws_size){ k_flag<<<1, 256, 0, stream>>>(out, 5000.f); return; }

  char* p = (char*)d_ws;
  bf16*  x      = (bf16*) (p + o_x);
  bf16*  xl     = (bf16*) (p + o_xl);
  bf16*  xr     = (bf16*) (p + o_xr);
  int*   counts = (int*)  (p + o_counts);
  int*   cursor = (int*)  (p + o_cursor);
  int*   row_start = (int*)(p + o_rs);
  int*   csr_src = (int*) (p + o_csrs);
  bf16*  wb0l   = (bf16*) (p + o_wb0l);
  bf16*  wb0r   = (bf16*) (p + o_wb0r);
  bf16*  wb1l   = (bf16*) (p + o_wb1l);
  bf16*  wb1r   = (bf16*) (p + o_wb1r);
  bf16*  wb2l   = (bf16*) (p + o_wb2l);
  bf16*  wb2r   = (bf16*) (p + o_wb2r);

  // ---- prep (zero + pack + gather) then CSR build ----
  k_prep<<<(Nn*16+255)/256, 256, 0, stream>>>(emb, node_ids, x, counts, cursor,
                                              Wl0, Wr0, Wl1, Wr1, Wl2, Wr2,
                                              wb0l, wb0r, wb1l, wb1r, wb2l, wb2r);
  k_count<<<(EP+255)/256, 256, 0, stream>>>(ei, counts);
  k_scan<<<1, 256, 0, stream>>>(counts, row_start);
  k_fill<<<(EP+255)/256, 256, 0, stream>>>(ei, row_start, cursor, csr_src);

  constexpr int MT = Nn/16;  // 1875
  int wgrid = (Nn+3)/4;      // 4 waves/block, 1 node per wave

  // ---------- layer 0: Fin=16 (pad 32), H=3, C=32 ----------
  k_linmfma<16,32,96><<<(MT*12+3)/4, 256, 0, stream>>>(x, wb0l, bl0, wb0r, br0, xl, xr);
  k_fused0v<<<wgrid, 256, 0, stream>>>(xl, xr, csr_src, row_start, att0, bo0, x);

  // ---------- layer 1: Fin=96, H=2, C=96 ----------
  k_linmfma<96,96,192><<<(MT*24+3)/4, 256, 0, stream>>>(x, wb1l, bl1, wb1r, br1, xl, xr);
  k_fused1v<<<wgrid, 256, 0, stream>>>(xl, xr, csr_src, row_start, att1, bo1, x);

  // ---------- layer 2: Fin=192, H=1, C=64 ----------
  k_linmfma<192,192,64><<<(MT*8+3)/4, 256, 0, stream>>>(x, wb2l, bl2, wb2r, br2, xl, xr);
  k_fused2<<<wgrid, 256, 0, stream>>>(xl, xr, csr_src, row_start, att2, bo2, x);

  // ---------- fused mean pool + head ----------
  k_poolhead<<<Gg, 256, 0, stream>>>(x, batch, demo, Wc1, bc1, Wc2, bc2, out);
}

// Round 29
// 393.469 us; speedup vs baseline: 1.4123x; 1.1346x over previous
//
#include <hip/hip_runtime.h>
#include <hip/hip_bf16.h>

typedef __hip_bfloat16 bf16;
typedef __attribute__((ext_vector_type(8))) short short8;
typedef __attribute__((ext_vector_type(4))) float f32x4;

static __device__ __forceinline__ float b2f(bf16 v){ return __bfloat162float(v); }
static __device__ __forceinline__ float blo(unsigned u){ return __uint_as_float(u<<16); }
static __device__ __forceinline__ float bhi(unsigned u){ return __uint_as_float(u & 0xffff0000u); }
static __device__ __forceinline__ int clampi(int v, int lo, int hi){
  return v < lo ? lo : (v > hi ? hi : v);
}
static __device__ __forceinline__ float rw16(float v){
  #pragma unroll
  for (int m=8;m>=1;m>>=1) v += __shfl_xor(v,m,64);
  return v;
}
// reduce within each 32-lane half (masks <=16 never cross halves)
static __device__ __forceinline__ float rw32h(float v){
  #pragma unroll
  for (int m=16;m>=1;m>>=1) v += __shfl_xor(v,m,64);
  return v;
}

constexpr int Nn = 30000;   // nodes
constexpr int E0 = 480000;  // edges (no self loops)
constexpr int EP = E0 + Nn; // edges incl self loops = 510000
constexpr int Gg = 128;     // graphs
constexpr int Vv = 10000;   // vocab size of emb

// ---------------- diagnostic flag (fp32 out) ----------------
__global__ void k_flag(float* __restrict__ out, float v){
  int t = blockIdx.x*blockDim.x + threadIdx.x;
  if (t < Gg*2) out[t] = v;
}

// ---------------- prep: zero CSR scratch + pack all W + gather emb (one launch) ----------------
__global__ void k_prep(const float* __restrict__ emb, const int* __restrict__ ids,
                       bf16* __restrict__ x,
                       int* __restrict__ counts, int* __restrict__ cursor,
                       const float* __restrict__ W0l, const float* __restrict__ W0r,
                       const float* __restrict__ W1l, const float* __restrict__ W1r,
                       const float* __restrict__ W2l, const float* __restrict__ W2r,
                       bf16* __restrict__ B0l, bf16* __restrict__ B0r,
                       bf16* __restrict__ B1l, bf16* __restrict__ B1r,
                       bf16* __restrict__ B2l, bf16* __restrict__ B2r){
  int t = blockIdx.x*blockDim.x + threadIdx.x;
  if (t < Nn){ counts[t] = 0; cursor[t] = 0; }
  if (t < 67584){
    const float* W; bf16* B; int K, F, Kp, i;
    if      (t <  3072){ i = t;       W = W0l; B = B0l; K=16;  F=96;  Kp=32;  }
    else if (t <  6144){ i = t-3072;  W = W0r; B = B0r; K=16;  F=96;  Kp=32;  }
    else if (t < 24576){ i = t-6144;  W = W1l; B = B1l; K=96;  F=192; Kp=96;  }
    else if (t < 43008){ i = t-24576; W = W1r; B = B1r; K=96;  F=192; Kp=96;  }
    else if (t < 55296){ i = t-43008; W = W2l; B = B2l; K=192; F=64;  Kp=192; }
    else               { i = t-55296; W = W2r; B = B2r; K=192; F=64;  Kp=192; }
    int o = i / Kp, k = i % Kp;
    float v = (k < K) ? W[k*F + o] : 0.f;
    B[i] = __float2bfloat16(v);
  }
  if (t < Nn*16){
    int n = t >> 4, c = t & 15;
    int id = clampi(ids[n], 0, Vv-1);
    x[t] = __float2bfloat16(emb[id*16 + c]);
  }
}

// ---------------- CSR build (by dst) ----------------
__global__ void k_count(const int* __restrict__ ei, int* __restrict__ counts){
  int e = blockIdx.x*blockDim.x + threadIdx.x;
  if (e >= EP) return;
  int dst = (e < E0) ? clampi(ei[E0 + e], 0, Nn-1) : (e - E0);
  atomicAdd(&counts[dst], 1);
}

__global__ void k_scan(const int* __restrict__ counts, int* __restrict__ row_start){
  __shared__ int s[256];
  constexpr int CH = (Nn + 255) / 256;  // 118
  int tid = threadIdx.x;
  int base = tid*CH;
  int t_sum = 0;
  for (int j=0;j<CH;j++){ int i = base+j; if (i<Nn) t_sum += counts[i]; }
  s[tid] = t_sum; __syncthreads();
  for (int off=1; off<256; off<<=1){
    int v = (tid>=off) ? s[tid-off] : 0;
    __syncthreads();
    s[tid] += v; __syncthreads();
  }
  int run = s[tid] - t_sum; // exclusive prefix
  for (int j=0;j<CH;j++){ int i = base+j; if (i<Nn){ row_start[i] = run; run += counts[i]; } }
  if (tid == 255) row_start[Nn] = s[255];
}

__global__ void k_fill(const int* __restrict__ ei, const int* __restrict__ row_start,
                       int* __restrict__ cursor, int* __restrict__ csr_src){
  int e = blockIdx.x*blockDim.x + threadIdx.x;
  if (e >= EP) return;
  int src = (e < E0) ? clampi(ei[e],      0, Nn-1) : (e - E0);
  int dst = (e < E0) ? clampi(ei[E0 + e], 0, Nn-1) : (e - E0);
  int pos = atomicAdd(&cursor[dst], 1);
  int i = row_start[dst] + pos;
  if (i < 0 || i >= EP) return;
  csr_src[i] = src;
}

// ---------------- MFMA dual linear: one wave = 16 nodes x 16 outputs ----------------
template<int K, int Kp, int Fout>
__global__ void k_linmfma(const bf16* __restrict__ x,
                          const bf16* __restrict__ Wbl, const float* __restrict__ bl,
                          const bf16* __restrict__ Wbr, const float* __restrict__ br,
                          bf16* __restrict__ yl, bf16* __restrict__ yr){
  constexpr int OT = Fout/16;
  constexpr int KSTEPS = Kp/32;
  int w = blockIdx.x*(blockDim.x>>6) + (threadIdx.x>>6);
  constexpr int MT = Nn/16;              // 1875 (exact)
  if (w >= MT * 2*OT) return;
  int mt  = w / (2*OT);
  int ot2 = w % (2*OT);
  bool isl = ot2 < OT;
  int o0 = (isl ? ot2 : ot2 - OT) * 16;
  const bf16*  Wb   = isl ? Wbl : Wbr;
  const float* bias = isl ? bl  : br;
  bf16*        y    = isl ? yl  : yr;

  int lane = threadIdx.x & 63;
  int l16  = lane & 15;
  int quad = lane >> 4;

  const bf16* arow = x  + (size_t)(mt*16 + l16)*K;
  const bf16* brow = Wb + (size_t)(o0 + l16)*Kp;

  f32x4 acc = {0.f,0.f,0.f,0.f};
  #pragma unroll
  for (int ks=0; ks<KSTEPS; ks++){
    int k0 = ks*32 + quad*8;
    short8 a;
    if (K == Kp || k0 < K) a = *(const short8*)(arow + k0);
    else                   a = short8{0,0,0,0,0,0,0,0};
    short8 b = *(const short8*)(brow + k0);
    acc = __builtin_amdgcn_mfma_f32_16x16x32_bf16(a, b, acc, 0, 0, 0);
  }

  float bo_ = bias[o0 + l16];
  #pragma unroll
  for (int r=0;r<4;r++){
    int m = mt*16 + quad*4 + r;
    y[(size_t)m*Fout + o0 + l16] = __float2bfloat16(acc[r] + bo_);
  }
}

// ================= layer 0 fused (H=3,C=32,HC=96): 2 ch/lane, rw16 head-reduce ================
template<int UN, bool MASK>
static __device__ __forceinline__
void grp0v(const bf16* __restrict__ xl, const int* __restrict__ csr_src,
           int i, int r1, int ch,
           float xr0, float xr1, float a0, float a1,
           float& acc0, float& acc1, float& ds){
  unsigned xw[UN]; float wm[UN];
  #pragma unroll
  for (int u=0;u<UN;u++){
    int iu = i+u;
    int ii = MASK ? ((iu<r1)? iu : (r1-1)) : iu;
    wm[u] = MASK ? ((iu<r1)?1.f:0.f) : 1.f;
    int src = clampi(csr_src[ii],0,Nn-1);
    xw[u] = *(const unsigned*)(xl + (size_t)src*96 + ch);
  }
  #pragma unroll
  for (int u=0;u<UN;u++){
    float c0 = blo(xw[u]), c1 = bhi(xw[u]);
    float v0 = c0+xr0; v0 = (v0>0.f)? v0 : 0.2f*v0;
    float v1 = c1+xr1; v1 = (v1>0.f)? v1 : 0.2f*v1;
    float t = a0*v0 + a1*v1;
    float hs = rw16(t);       // heads align to 16-lane groups
    float p = __expf(hs);
    if (MASK) p *= wm[u];
    acc0 += p*c0; acc1 += p*c1; ds += p;
  }
}

__global__ void k_fused0v(const bf16* __restrict__ xl, const bf16* __restrict__ xr,
                          const int* __restrict__ csr_src, const int* __restrict__ row_start,
                          const float* __restrict__ att, const float* __restrict__ bo,
                          bf16* __restrict__ y){
  int n = blockIdx.x*(blockDim.x>>6) + (threadIdx.x>>6);
  if (n >= Nn) return;
  int lane = threadIdx.x & 63;
  bool act = lane < 48;
  int ch = act ? 2*lane : 0;
  int r0 = clampi(row_start[n],0,EP), r1 = clampi(row_start[n+1],0,EP);
  unsigned xrw = *(const unsigned*)(xr + (size_t)n*96 + ch);
  float xr0 = blo(xrw), xr1 = bhi(xrw);
  float a0=0.f, a1=0.f;
  if (act){ float2 av = *(const float2*)(att + ch); a0=av.x; a1=av.y; }
  float acc0=0.f, acc1=0.f, ds=0.f;
  int i=r0;
  for (; i+8<=r1; i+=8) grp0v<8,false>(xl,csr_src,i,r1,ch,xr0,xr1,a0,a1,acc0,acc1,ds);
  for (; i<r1; i+=4)    grp0v<4,true >(xl,csr_src,i,r1,ch,xr0,xr1,a0,a1,acc0,acc1,ds);
  if (act){
    float inv = 1.f/fmaxf(ds,1e-30f);
    y[(size_t)n*96 + ch  ] = __float2bfloat16(acc0*inv + bo[ch]);
    y[(size_t)n*96 + ch+1] = __float2bfloat16(acc1*inv + bo[ch+1]);
  }
}

// ====== layer 1 fused (H=2,C=96,HC=192): head-per-half, 4 ch/lane, 5-shuffle half-reduce ======
// head0 -> lanes 0..23 (ch 0..95), head1 -> lanes 32..55 (ch 96..191); lanes 24-31/56-63 idle.
template<int UN, bool MASK>
static __device__ __forceinline__
void grp1v(const bf16* __restrict__ xl, const int* __restrict__ csr_src,
           int i, int r1, int ch,
           const float* xrv, const float* av,
           float* acc, float& ds){
  uint2 xw[UN]; float wm[UN];
  #pragma unroll
  for (int u=0;u<UN;u++){
    int iu = i+u;
    int ii = MASK ? ((iu<r1)? iu : (r1-1)) : iu;
    wm[u] = MASK ? ((iu<r1)?1.f:0.f) : 1.f;
    int src = clampi(csr_src[ii],0,Nn-1);
    xw[u] = *(const uint2*)(xl + (size_t)src*192 + ch);
  }
  #pragma unroll
  for (int u=0;u<UN;u++){
    float c0 = blo(xw[u].x), c1 = bhi(xw[u].x), c2 = blo(xw[u].y), c3 = bhi(xw[u].y);
    float v0 = c0+xrv[0]; v0 = (v0>0.f)? v0 : 0.2f*v0;
    float v1 = c1+xrv[1]; v1 = (v1>0.f)? v1 : 0.2f*v1;
    float v2 = c2+xrv[2]; v2 = (v2>0.f)? v2 : 0.2f*v2;
    float v3 = c3+xrv[3]; v3 = (v3>0.f)? v3 : 0.2f*v3;
    float ts = av[0]*v0 + av[1]*v1 + av[2]*v2 + av[3]*v3;   // 0 on idle lanes (av=0)
    float hs = rw32h(ts);            // per-half reduce -> own head's logit
    float p = __expf(hs);
    if (MASK) p *= wm[u];
    acc[0]+=p*c0; acc[1]+=p*c1; acc[2]+=p*c2; acc[3]+=p*c3; ds+=p;
  }
}

__global__ void k_fused1v(const bf16* __restrict__ xl, const bf16* __restrict__ xr,
                          const int* __restrict__ csr_src, const int* __restrict__ row_start,
                          const float* __restrict__ att, const float* __restrict__ bo,
                          bf16* __restrict__ y){
  int n = blockIdx.x*(blockDim.x>>6) + (threadIdx.x>>6);
  if (n >= Nn) return;
  int lane = threadIdx.x & 63;
  int hl = lane & 31;
  int head = lane >> 5;
  bool act = hl < 24;
  int ch = head*96 + (act ? 4*hl : 0);
  int r0 = clampi(row_start[n],0,EP), r1 = clampi(row_start[n+1],0,EP);
  uint2 xrw = *(const uint2*)(xr + (size_t)n*192 + ch);
  float xrv[4] = { blo(xrw.x), bhi(xrw.x), blo(xrw.y), bhi(xrw.y) };
  float av[4] = {0.f,0.f,0.f,0.f};
  if (act){ float4 a4 = *(const float4*)(att + ch); av[0]=a4.x; av[1]=a4.y; av[2]=a4.z; av[3]=a4.w; }
  float acc[4] = {0.f,0.f,0.f,0.f};
  float ds = 0.f;
  int i=r0;
  for (; i+8<=r1; i+=8) grp1v<8,false>(xl,csr_src,i,r1,ch,xrv,av,acc,ds);
  for (; i<r1; i+=4)    grp1v<4,true >(xl,csr_src,i,r1,ch,xrv,av,acc,ds);
  if (act){
    float inv = 1.f/fmaxf(ds,1e-30f);
    #pragma unroll
    for (int j=0;j<4;j++)
      y[(size_t)n*192 + ch + j] = __float2bfloat16(acc[j]*inv + bo[ch+j]);
  }
}

// ====== layer 2 fused (H=1,C=64): half-wave per edge -> 2 edges per iteration ======
template<int UN, bool MASK>   // UN pairs = 2*UN edges
static __device__ __forceinline__
void grp2v(const bf16* __restrict__ xl, const int* __restrict__ csr_src,
           int i, int r1, int half, int ch,
           float xr0, float xr1, float a0, float a1,
           float& acc0, float& acc1, float& ds){
  unsigned xw[UN]; float wm[UN];
  #pragma unroll
  for (int u=0;u<UN;u++){
    int iu = i + 2*u + half;
    int ii = MASK ? ((iu<r1)? iu : (r1-1)) : iu;
    wm[u] = MASK ? ((iu<r1)?1.f:0.f) : 1.f;
    int src = clampi(csr_src[ii],0,Nn-1);
    xw[u] = *(const unsigned*)(xl + (size_t)src*64 + ch);
  }
  #pragma unroll
  for (int u=0;u<UN;u++){
    float c0 = blo(xw[u]), c1 = bhi(xw[u]);
    float v0 = c0+xr0; v0 = (v0>0.f)? v0 : 0.2f*v0;
    float v1 = c1+xr1; v1 = (v1>0.f)? v1 : 0.2f*v1;
    float t = a0*v0 + a1*v1;
    float hs = rw32h(t);          // edge's full 64-ch logit within this half
    float p = __expf(hs);
    if (MASK) p *= wm[u];
    acc0 += p*c0; acc1 += p*c1; ds += p;
  }
}

__global__ void k_fused2v(const bf16* __restrict__ xl, const bf16* __restrict__ xr,
                          const int* __restrict__ csr_src, const int* __restrict__ row_start,
                          const float* __restrict__ att, const float* __restrict__ bo,
                          bf16* __restrict__ y){
  int n = blockIdx.x*(blockDim.x>>6) + (threadIdx.x>>6);
  if (n >= Nn) return;
  int lane = threadIdx.x & 63;
  int half = lane >> 5;
  int ch = 2*(lane & 31);         // 0..62
  int r0 = clampi(row_start[n],0,EP), r1 = clampi(row_start[n+1],0,EP);
  unsigned xrw = *(const unsigned*)(xr + (size_t)n*64 + ch);
  float xr0 = blo(xrw), xr1 = bhi(xrw);
  float2 av = *(const float2*)(att + ch);
  float acc0=0.f, acc1=0.f, ds=0.f;
  int i=r0;
  for (; i+8<=r1; i+=8) grp2v<4,false>(xl,csr_src,i,r1,half,ch,xr0,xr1,av.x,av.y,acc0,acc1,ds);
  for (; i<r1; i+=2)    grp2v<1,true >(xl,csr_src,i,r1,half,ch,xr0,xr1,av.x,av.y,acc0,acc1,ds);
  // combine the two halves' partial sums (same channels, disjoint edges)
  acc0 += __shfl_xor(acc0, 32, 64);
  acc1 += __shfl_xor(acc1, 32, 64);
  ds   += __shfl_xor(ds,   32, 64);
  if (half == 0){
    float inv = 1.f/fmaxf(ds,1e-30f);
    y[(size_t)n*64 + ch  ] = __float2bfloat16(acc0*inv + bo[ch]);
    y[(size_t)n*64 + ch+1] = __float2bfloat16(acc1*inv + bo[ch+1]);
  }
}

// ---------------- mean pool + classifier head fused: one block per graph ----------------
__global__ void k_poolhead(const bf16* __restrict__ x, const int* __restrict__ batch,
                           const float* __restrict__ demo,
                           const float* __restrict__ Wc1, const float* __restrict__ bc1,
                           const float* __restrict__ Wc2, const float* __restrict__ bc2,
                           float* __restrict__ out){
  __shared__ float sh[4][64];
  __shared__ float h0[69];
  __shared__ float h1[32];
  int g = blockIdx.x;
  int t = threadIdx.x;          // 256 threads = 4 waves
  int c = t & 63;
  int w = t >> 6;
  int a = 0, b = Nn;
  while (a < b){ int m = (a+b)>>1; if (clampi(batch[m],0,Gg-1) < g) a = m+1; else b = m; }
  int lo = a;
  b = Nn;
  while (a < b){ int m = (a+b)>>1; if (clampi(batch[m],0,Gg-1) <= g) a = m+1; else b = m; }
  int hi = a;

  float s = 0.f;
  for (int n = lo + w; n < hi; n += 4)
    s += b2f(x[(size_t)n*64 + c]);
  sh[w][c] = s;
  __syncthreads();
  float invc = 1.f / fmaxf((float)(hi - lo), 1.f);
  if (t < 64) h0[t] = (sh[0][t] + sh[1][t] + sh[2][t] + sh[3][t]) * invc;
  else if (t < 69) h0[t] = demo[g*5 + (t - 64)];
  __syncthreads();
  if (t < 32){
    float v = bc1[t];
    for (int k=0;k<69;k++) v += h0[k]*Wc1[k*32 + t];
    h1[t] = fmaxf(v, 0.f);
  }
  __syncthreads();
  if (t < 2){
    float v = bc2[t];
    for (int k=0;k<32;k++) v += h1[k]*Wc2[k*2 + t];
    out[g*2 + t] = v;
  }
}

extern "C" void kernel_launch(void* const* d_in, const int* in_sizes, int n_in,
                              void* d_out, int out_size, void* d_ws, size_t ws_size,
                              hipStream_t stream) {
  const float* emb  = (const float*)d_in[0];
  const float* Wl0  = (const float*)d_in[1];
  const float* bl0  = (const float*)d_in[2];
  const float* Wr0  = (const float*)d_in[3];
  const float* br0  = (const float*)d_in[4];
  const float* att0 = (const float*)d_in[5];
  const float* bo0  = (const float*)d_in[6];
  const float* Wl1  = (const float*)d_in[7];
  const float* bl1  = (const float*)d_in[8];
  const float* Wr1  = (const float*)d_in[9];
  const float* br1  = (const float*)d_in[10];
  const float* att1 = (const float*)d_in[11];
  const float* bo1  = (const float*)d_in[12];
  const float* Wl2  = (const float*)d_in[13];
  const float* bl2  = (const float*)d_in[14];
  const float* Wr2  = (const float*)d_in[15];
  const float* br2  = (const float*)d_in[16];
  const float* att2 = (const float*)d_in[17];
  const float* bo2  = (const float*)d_in[18];
  const float* Wc1  = (const float*)d_in[19];
  const float* bc1  = (const float*)d_in[20];
  const float* Wc2  = (const float*)d_in[21];
  const float* bc2  = (const float*)d_in[22];
  const float* demo = (const float*)d_in[23];
  const int* node_ids = (const int*)d_in[24];
  const int* ei       = (const int*)d_in[25];
  const int* batch    = (const int*)d_in[26];
  float* out = (float*)d_out;

  // ---- sentinel 4000: input ordering/sizes ----
  bool ok = (n_in == 27) && (out_size == Gg*2)
         && (in_sizes[0]  == Vv*16) && (in_sizes[1]  == 16*96)
         && (in_sizes[7]  == 96*192) && (in_sizes[13] == 192*64)
         && (in_sizes[19] == 69*32) && (in_sizes[23] == Gg*5)
         && (in_sizes[24] == Nn) && (in_sizes[25] == 2*E0) && (in_sizes[26] == Nn);
  if (!ok){ k_flag<<<1, 256, 0, stream>>>(out, 4000.f); return; }

  // ---- workspace layout (sentinel 5000 if too small) ----
  size_t need = 0;
  auto plan = [&](size_t bytes){ size_t r = need; need += (bytes + 255) & ~(size_t)255; return r; };
  size_t o_x      = plan((size_t)Nn*192*2);   // bf16 node features
  size_t o_xl     = plan((size_t)Nn*192*2);   // bf16 staging
  size_t o_xr     = plan((size_t)Nn*192*2);   // bf16 staging
  size_t o_counts = plan((size_t)Nn*4);
  size_t o_cursor = plan((size_t)Nn*4);
  size_t o_rs     = plan((size_t)(Nn+1)*4);
  size_t o_csrs   = plan((size_t)EP*4);
  size_t o_wb0l   = plan((size_t)96*32*2);
  size_t o_wb0r   = plan((size_t)96*32*2);
  size_t o_wb1l   = plan((size_t)192*96*2);
  size_t o_wb1r   = plan((size_t)192*96*2);
  size_t o_wb2l   = plan((size_t)64*192*2);
  size_t o_wb2r   = plan((size_t)64*192*2);
  if (need > ws_size){ k_flag<<<1, 256, 0, stream>>>(out, 5000.f); return; }

  char* p = (char*)d_ws;
  bf16*  x      = (bf16*) (p + o_x);
  bf16*  xl     = (bf16*) (p + o_xl);
  bf16*  xr     = (bf16*) (p + o_xr);
  int*   counts = (int*)  (p + o_counts);
  int*   cursor = (int*)  (p + o_cursor);
  int*   row_start = (int*)(p + o_rs);
  int*   csr_src = (int*) (p + o_csrs);
  bf16*  wb0l   = (bf16*) (p + o_wb0l);
  bf16*  wb0r   = (bf16*) (p + o_wb0r);
  bf16*  wb1l   = (bf16*) (p + o_wb1l);
  bf16*  wb1r   = (bf16*) (p + o_wb1r);
  bf16*  wb2l   = (bf16*) (p + o_wb2l);
  bf16*  wb2r   = (bf16*) (p + o_wb2r);

  // ---- prep (zero + pack + gather) then CSR build ----
  k_prep<<<(Nn*16+255)/256, 256, 0, stream>>>(emb, node_ids, x, counts, cursor,
                                              Wl0, Wr0, Wl1, Wr1, Wl2, Wr2,
                                              wb0l, wb0r, wb1l, wb1r, wb2l, wb2r);
  k_count<<<(EP+255)/256, 256, 0, stream>>>(ei, counts);
  k_scan<<<1, 256, 0, stream>>>(counts, row_start);
  k_fill<<<(EP+255)/256, 256, 0, stream>>>(ei, row_start, cursor, csr_src);

  constexpr int MT = Nn/16;  // 1875
  int wgrid = (Nn+3)/4;      // 4 waves/block, 1 node per wave

  // ---------- layer 0: Fin=16 (pad 32), H=3, C=32 ----------
  k_linmfma<16,32,96><<<(MT*12+3)/4, 256, 0, stream>>>(x, wb0l, bl0, wb0r, br0, xl, xr);
  k_fused0v<<<wgrid, 256, 0, stream>>>(xl, xr, csr_src, row_start, att0, bo0, x);

  // ---------- layer 1: Fin=96, H=2, C=96 ----------
  k_linmfma<96,96,192><<<(MT*24+3)/4, 256, 0, stream>>>(x, wb1l, bl1, wb1r, br1, xl, xr);
  k_fused1v<<<wgrid, 256, 0, stream>>>(xl, xr, csr_src, row_start, att1, bo1, x);

  // ---------- layer 2: Fin=192, H=1, C=64 ----------
  k_linmfma<192,192,64><<<(MT*8+3)/4, 256, 0, stream>>>(x, wb2l, bl2, wb2r, br2, xl, xr);
  k_fused2v<<<wgrid, 256, 0, stream>>>(xl, xr, csr_src, row_start, att2, bo2, x);

  // ---------- fused mean pool + head ----------
  k_poolhead<<<Gg, 256, 0, stream>>>(x, batch, demo, Wc1, bc1, Wc2, bc2, out);
}